// Round 8
// baseline (36.281 us; speedup 1.0000x reference)
//
#include <hip/hip_runtime.h>
#include <math.h>

#define TPB 64                // single-wave WGs; 16 WGs/CU at 9.2KB LDS
#define NQ 2                  // matrices per thread, paired in v2 lanes
#define CHUNK (TPB * NQ)      // 128 matrices per chunk
#define CH_F (CHUNK * 9)      // 1152 floats per chunk
#define CH_F4 (CH_F / 4)      // 288 float4 per chunk
#define NSTG 5                // DMA ops per STAGE per wave -- ALWAYS exactly 5

typedef float v2  __attribute__((ext_vector_type(2)));
typedef int   v2i __attribute__((ext_vector_type(2)));

static __device__ __forceinline__ v2 V2(float x){ v2 r; r.x=x; r.y=x; return r; }
static __device__ __forceinline__ v2 vfma(v2 a, v2 b, v2 c){ return __builtin_elementwise_fma(a, b, c); }
static __device__ __forceinline__ v2 vmax(v2 a, v2 b){ return __builtin_elementwise_max(a, b); }
static __device__ __forceinline__ v2 vabs(v2 a){ return __builtin_elementwise_abs(a); }
static __device__ __forceinline__ v2 vcps(v2 a, v2 b){ return __builtin_elementwise_copysign(a, b); }

static __device__ __forceinline__ v2 rsq2(v2 x){ v2 r; r.x=__builtin_amdgcn_rsqf(x.x);  r.y=__builtin_amdgcn_rsqf(x.y);  return r; }
static __device__ __forceinline__ v2 rcp2(v2 x){ v2 r; r.x=__builtin_amdgcn_rcpf(x.x);  r.y=__builtin_amdgcn_rcpf(x.y);  return r; }
static __device__ __forceinline__ v2 sqt2(v2 x){ v2 r; r.x=__builtin_amdgcn_sqrtf(x.x); r.y=__builtin_amdgcn_sqrtf(x.y); return r; }
static __device__ __forceinline__ v2 lg22(v2 x){ v2 r; r.x=__builtin_amdgcn_logf(x.x);  r.y=__builtin_amdgcn_logf(x.y);  return r; }
static __device__ __forceinline__ v2 ex22(v2 x){ v2 r; r.x=__builtin_amdgcn_exp2f(x.x); r.y=__builtin_amdgcn_exp2f(x.y); return r; }

static __device__ __forceinline__ v2 vsel(v2i m, v2 a, v2 b){
  v2i ai = __builtin_bit_cast(v2i, a), bi = __builtin_bit_cast(v2i, b);
  return __builtin_bit_cast(v2, bi ^ ((ai ^ bi) & m));
}

// async global->LDS DMA, 16B/lane; LDS dest = wave-uniform base + lane*16
static __device__ __forceinline__ void gl_lds16(const float* g, float* l){
  __builtin_amdgcn_global_load_lds(
      (const __attribute__((address_space(1))) void*)g,
      (__attribute__((address_space(3))) void*)l, 16, 0, 0);
}

// Exact Jacobi rotation for [[app,apq],[apq,aqq]] via half-angle form.
// 1e-30f clamp is a representable normal: degenerate case -> identity, NaN-free.
__device__ __forceinline__ void jcs2(v2 app_in, v2 aqq_in, v2 apq,
                                     v2& c, v2& s,
                                     v2& app_out, v2& aqq_out)
{
  v2 d    = (aqq_in - app_in) * 0.5f;
  v2 r2   = vmax(vfma(d, d, apq * apq), V2(1e-30f));
  v2 invh = rsq2(r2);
  v2 h    = r2 * invh;                       // sqrt(d^2 + apq^2)
  v2 sg   = vcps(V2(1.0f), d);
  v2 ch   = h + vabs(d);
  v2 sh   = apq * sg;
  v2 w    = rsq2(vfma(ch, ch, sh * sh));
  c = ch * w;
  s = sh * w;
  v2 hs = h * sg;
  v2 m  = app_in + d;
  app_out = m - hs;
  aqq_out = m + hs;
}

__device__ __forceinline__ void jrot(v2& app, v2& aqq, v2& apq,
                                     v2& apk, v2& aqk,
                                     v2& vp0, v2& vp1, v2& vp2,
                                     v2& vq0, v2& vq1, v2& vq2)
{
  v2 c, s;
  jcs2(app, aqq, apq, c, s, app, aqq);
  apq = V2(0.0f);
  v2 pk = apk, qk = aqk;
  apk = c * pk - s * qk;
  aqk = s * pk + c * qk;
  v2 v;
  v = vp0; vp0 = c*v - s*vq0; vq0 = s*v + c*vq0;
  v = vp1; vp1 = c*v - s*vq1; vq1 = s*v + c*vq1;
  v = vp2; vp2 = c*v - s*vq2; vq2 = s*v + c*vq2;
}

#define CSWAP(li, lj, a0, a1, a2, b0, b1, b2)                                   \
  do {                                                                          \
    v2i _m = (li) < (lj);                                                       \
    v2 _t;                                                                      \
    _t = vsel(_m,(lj),(li)); (lj) = vsel(_m,(li),(lj)); (li) = _t;              \
    _t = vsel(_m,(b0),(a0)); (b0) = vsel(_m,(a0),(b0)); (a0) = _t;              \
    _t = vsel(_m,(b1),(a1)); (b1) = vsel(_m,(a1),(b1)); (a1) = _t;              \
    _t = vsel(_m,(b2),(a2)); (b2) = vsel(_m,(a2),(b2)); (a2) = _t;              \
  } while (0)

__global__ __launch_bounds__(TPB) void plastic_svd_kernel(
    const float* __restrict__ F,
    const float* __restrict__ p_yml,
    const float* __restrict__ p_nu,
    const float* __restrict__ p_ys,
    float* __restrict__ out,
    int nmat, int nchunks)
{
  __shared__ float lds[2][CH_F];             // 9.2 KB double buffer
  const int tid = threadIdx.x;
  const int totF  = nmat * 9;
  const int totF4 = totF >> 2;

  // uniform scalar parameters (once per WG lifetime)
  const float mu_s = __builtin_amdgcn_exp2f(p_yml[0] * 1.44269504f) *
                     __builtin_amdgcn_rcpf(2.0f * (1.0f + p_nu[0]));
  const float qy_s = p_ys[0] * 0.5f * __builtin_amdgcn_rcpf(mu_s);
  const v2 qy = V2(qy_s);

  // Stage chunk t into buffer b. EXACTLY NSTG(=5) vmem ops per wave:
  // the global index is CLAMPED (never exec-skipped), so the counted
  // s_waitcnt vmcnt(NSTG) in the loop is always exact. Clamped lanes load
  // duplicate valid data (finite floats -> NaN-free), discarded by store guards.
  auto STAGE = [&](int t, int b){
    const int f4base = t * CH_F4;
    #pragma unroll
    for (int k = 0; k < 5; ++k) {
      int i4 = k * TPB + tid;
      if (i4 < CH_F4) {                      // k=4: lanes 0-31 (still 1 DMA op)
        int gi4 = f4base + i4;
        gi4 = gi4 < totF4 ? gi4 : totF4 - 1; // clamp keeps op count fixed
        gl_lds16((const float*)((const float4*)F + gi4), &lds[b][i4 * 4]);
      }
    }
    // general-shape tail (totF % 4 != 0): plain loads, only on last chunk.
    // Never executes for this problem (2M*9 % 4 == 0).
    if ((totF & 3) && t == nchunks - 1) {
      int e = (totF & ~3) + tid;
      if (e < totF) lds[b][e - t * CH_F] = F[e];
    }
  };

  int cur = 0;
  const int t0 = blockIdx.x;
  STAGE(t0, 0);                              // prologue: 5 DMA outstanding

  for (int t = t0; t < nchunks; t += gridDim.x) {
    const int tn = t + gridDim.x;
    const bool pf = tn < nchunks;
    if (pf) {
      STAGE(tn, cur ^ 1);                    // +5 DMA (newest)
      // counted wait: drain everything EXCEPT the 5 newest (the prefetch).
      // Retires chunk t's DMA and all older stores; prefetch stays in flight.
      asm volatile("s_waitcnt vmcnt(5)" ::: "memory");
    } else {
      asm volatile("s_waitcnt vmcnt(0)" ::: "memory");  // final chunk
    }
    __builtin_amdgcn_sched_barrier(0);

    const int blockBase = t * CHUNK;
    const int gbase = blockBase * 9;
    const int mi0 = blockBase + tid;         // lane .x matrix
    const int mi1 = blockBase + TPB + tid;   // lane .y matrix
    float* bufc = lds[cur];
    const float* mA = &bufc[tid * 9];        // stride-9: 2 lanes/bank, free
    const float* mB = &bufc[(TPB + tid) * 9];

    // ---- F -> registers ONCE (kept live: 16-WG/CU regime is LDS-capped,
    //      VGPR up to 128 is free -> no LDS re-read needed) ----
    v2 f00,f01,f02,f10,f11,f12,f20,f21,f22;
    f00.x=mA[0]; f01.x=mA[1]; f02.x=mA[2];
    f10.x=mA[3]; f11.x=mA[4]; f12.x=mA[5];
    f20.x=mA[6]; f21.x=mA[7]; f22.x=mA[8];
    f00.y=mB[0]; f01.y=mB[1]; f02.y=mB[2];
    f10.y=mB[3]; f11.y=mB[4]; f12.y=mB[5];
    f20.y=mB[6]; f21.y=mB[7]; f22.y=mB[8];

    // ---- S = F^T F ----
    v2 s00 = f00*f00 + f10*f10 + f20*f20;
    v2 s11 = f01*f01 + f11*f11 + f21*f21;
    v2 s22 = f02*f02 + f12*f12 + f22*f22;
    v2 s01 = f00*f01 + f10*f11 + f20*f21;
    v2 s02 = f00*f02 + f10*f12 + f20*f22;
    v2 s12 = f01*f02 + f11*f12 + f21*f22;

    v2 v00,v01,v02,v10,v11,v12,v20,v21,v22;
    v2 c, s;

    // ---- sweep 1, rot (0,1): V = I specialization ----
    jcs2(s00, s11, s01, c, s, s00, s11);
    { v2 pk = s02, qk = s12; s02 = c*pk - s*qk; s12 = s*pk + c*qk; }
    v00 = c;  v01 = s;
    v10 = -s; v11 = c;
    s01 = V2(0.0f);
    // ---- sweep 1, rot (0,2): col2 still e3, col0 = (v00,v10,0) ----
    jcs2(s00, s22, s02, c, s, s00, s22);
    { v2 pk = s01, qk = s12; s01 = c*pk - s*qk; s12 = s*pk + c*qk; }
    v02 = s * v00; v12 = s * v10; v22 = c;
    v00 = c * v00; v10 = c * v10; v20 = -s;
    v21 = V2(0.0f);
    s02 = V2(0.0f);
    // ---- sweep 1, rot (1,2) ----
    jrot(s11, s22, s12, s01, s02, v01, v11, v21, v02, v12, v22);
    // ---- sweep 2 ----
    jrot(s00, s11, s01, s02, s12, v00, v10, v20, v01, v11, v21);
    jrot(s00, s22, s02, s01, s12, v00, v10, v20, v02, v12, v22);
    jrot(s11, s22, s12, s01, s02, v01, v11, v21, v02, v12, v22);
    // ---- sweep 3 ----
    jrot(s00, s11, s01, s02, s12, v00, v10, v20, v01, v11, v21);
    jrot(s00, s22, s02, s01, s12, v00, v10, v20, v02, v12, v22);
    // final rot (1,2): couplings dead; diag still updated (closed form).
    jcs2(s11, s22, s12, c, s, s11, s22);
    { v2 v;
      v = v01; v01 = c*v - s*v02; v02 = s*v + c*v02;
      v = v11; v11 = c*v - s*v12; v12 = s*v + c*v12;
      v = v21; v21 = c*v - s*v22; v22 = s*v + c*v22; }

    // ---- sort eigenvalues descending (GS conditioning: R2 lesson) ----
    v2 l0 = s00, l1 = s11, l2 = s22;
    CSWAP(l0, l1, v00, v10, v20, v01, v11, v21);
    CSWAP(l1, l2, v01, v11, v21, v02, v12, v22);
    CSWAP(l0, l1, v00, v10, v20, v01, v11, v21);

    // ---- U: u0 = Fv0/|Fv0|; u1 = GS; u2 = u0 x u1 (sign-fixed) ----
    v2 w0x = f00*v00 + f01*v10 + f02*v20;
    v2 w0y = f10*v00 + f11*v10 + f12*v20;
    v2 w0z = f20*v00 + f21*v10 + f22*v20;
    v2 n0sq = w0x*w0x + w0y*w0y + w0z*w0z;
    v2 inv0 = rsq2(vmax(n0sq, V2(1e-30f)));
    v2 u0x = w0x*inv0, u0y = w0y*inv0, u0z = w0z*inv0;

    v2 w1x = f00*v01 + f01*v11 + f02*v21;
    v2 w1y = f10*v01 + f11*v11 + f12*v21;
    v2 w1z = f20*v01 + f21*v11 + f22*v21;
    v2 n1sq_pre = w1x*w1x + w1y*w1y + w1z*w1z;  // = sigma1^2 (pre-GS)
    v2 d01 = w1x*u0x + w1y*u0y + w1z*u0z;
    w1x = w1x - d01*u0x; w1y = w1y - d01*u0y; w1z = w1z - d01*u0z;
    v2 n1sq = w1x*w1x + w1y*w1y + w1z*w1z;
    v2 inv1 = rsq2(vmax(n1sq, V2(1e-30f)));
    v2 u1x = w1x*inv1, u1y = w1y*inv1, u1z = w1z*inv1;

    v2 u2x = u0y*u1z - u0z*u1y;
    v2 u2y = u0z*u1x - u0x*u1z;
    v2 u2z = u0x*u1y - u0y*u1x;
    v2 w2x = f00*v02 + f01*v12 + f02*v22;
    v2 w2y = f10*v02 + f11*v12 + f12*v22;
    v2 w2z = f20*v02 + f21*v12 + f22*v22;
    v2 s2d = u2x*w2x + u2y*w2y + u2z*w2z;
    v2 sg = vcps(V2(1.0f), s2d);             // sign-fix for det(U)=+1
    v2 sig2 = vabs(s2d);
    u2x = u2x * sg; u2y = u2y * sg; u2z = u2z * sg;

    // ---- von-Mises return mapping, base-2 internally ----
    v2 e0 = lg22(vmax(n0sq,     V2(1e-4f))) * 0.5f;
    v2 e1 = lg22(vmax(n1sq_pre, V2(1e-4f))) * 0.5f;
    v2 e2 = lg22(vmax(sig2,     V2(0.01f)));
    v2 m3 = (e0 + e1 + e2) * (1.0f / 3.0f);
    v2 b0 = e0 - m3, b1 = e1 - m3, b2 = e2 - m3;
    v2 bn = sqt2(b0*b0 + b1*b1 + b2*b2) * 0.69314718f + V2(1e-5f);
    v2 r = vmax(bn - qy, V2(0.0f)) * rcp2(bn);   // 0 if elastic
    v2 c0 = ex22(e0 - r * b0);
    v2 c1 = ex22(e1 - r * b1);
    v2 c2 = ex22(e2 - r * b2);

    // ---- out = sum_i c_i u_i v_i^T ----
    v2 a0x = c0*u0x, a0y = c0*u0y, a0z = c0*u0z;
    v2 a1x = c1*u1x, a1y = c1*u1y, a1z = c1*u1z;
    v2 a2x = c2*u2x, a2y = c2*u2y, a2z = c2*u2z;

    v2 o00 = a0x*v00 + a1x*v01 + a2x*v02;
    v2 o01 = a0x*v10 + a1x*v11 + a2x*v12;
    v2 o02 = a0x*v20 + a1x*v21 + a2x*v22;
    v2 o10 = a0y*v00 + a1y*v01 + a2y*v02;
    v2 o11 = a0y*v10 + a1y*v11 + a2y*v12;
    v2 o12 = a0y*v20 + a1y*v21 + a2y*v22;
    v2 o20 = a0z*v00 + a1z*v01 + a2z*v02;
    v2 o21 = a0z*v10 + a1z*v11 + a2z*v12;
    v2 o22 = a0z*v20 + a1z*v21 + a2z*v22;

    // ---- stage outputs into bufc (F consumed; own slots) ----
    if (mi0 < nmat) {
      float* m = &bufc[tid * 9];
      m[0]=o00.x; m[1]=o01.x; m[2]=o02.x;
      m[3]=o10.x; m[4]=o11.x; m[5]=o12.x;
      m[6]=o20.x; m[7]=o21.x; m[8]=o22.x;
    }
    if (mi1 < nmat) {
      float* m = &bufc[(TPB + tid) * 9];
      m[0]=o00.y; m[1]=o01.y; m[2]=o02.y;
      m[3]=o10.y; m[4]=o11.y; m[5]=o12.y;
      m[6]=o20.y; m[7]=o21.y; m[8]=o22.y;
    }
    // LDS-only fence: orders cross-lane ds_write->ds_read WITHOUT touching
    // vmcnt (the prefetch DMA stays in flight).
    asm volatile("s_waitcnt lgkmcnt(0)" ::: "memory");
    __builtin_amdgcn_sched_barrier(0);

    // ---- coalesced LDS -> global store, float4-wide (fire-and-forget) ----
    {
      const int rem = nmat - blockBase;
      const int nfl = (rem >= CHUNK ? CHUNK : rem) * 9;
      const int nfl4 = nfl >> 2;
      float4* g4 = (float4*)(out + gbase);
      const float4* l4 = (const float4*)bufc;
      #pragma unroll
      for (int k = 0; k < 5; ++k) {
        int i4 = k * TPB + tid;
        if (i4 < CH_F4 && i4 < nfl4) g4[i4] = l4[i4];
      }
      int i = (nfl & ~3) + tid;
      if (i < nfl) out[gbase + i] = bufc[i];
    }
    cur ^= 1;
  }
}

extern "C" void kernel_launch(void* const* d_in, const int* in_sizes, int n_in,
                              void* d_out, int out_size, void* d_ws, size_t ws_size,
                              hipStream_t stream) {
  const float* F     = (const float*)d_in[0];
  const float* p_yml = (const float*)d_in[1];
  const float* p_nu  = (const float*)d_in[2];
  const float* p_ys  = (const float*)d_in[3];
  float* out = (float*)d_out;

  const int nmat = in_sizes[0] / 9;
  const int nchunks = (nmat + CHUNK - 1) / CHUNK;
  // persistent grid: 16 single-wave WGs per CU (9.2KB x 16 = 147KB < 160KB)
  int G = 16 * 256;
  if (G > nchunks) G = nchunks;
  hipLaunchKernelGGL(plastic_svd_kernel, dim3(G), dim3(TPB), 0, stream,
                     F, p_yml, p_nu, p_ys, out, nmat, nchunks);
}

// Round 9
// 35.071 us; speedup vs baseline: 1.0345x; 1.0345x over previous
//
#include <hip/hip_runtime.h>
#include <math.h>

#define TPB 64                // single-wave WGs: no real barriers needed
#define NQ 2                  // matrices per thread, paired in v2 lanes
#define CHUNK (TPB * NQ)      // 128 matrices per chunk
#define CH_F (CHUNK * 9)      // 1152 floats per chunk
#define CH_F4 (CH_F / 4)      // 288 float4 per chunk
#define NCH 4                 // chunks per block (1-deep reg prefetch pipeline)

typedef float v2  __attribute__((ext_vector_type(2)));
typedef int   v2i __attribute__((ext_vector_type(2)));

static __device__ __forceinline__ v2 V2(float x){ v2 r; r.x=x; r.y=x; return r; }
static __device__ __forceinline__ v2 vfma(v2 a, v2 b, v2 c){ return __builtin_elementwise_fma(a, b, c); }
static __device__ __forceinline__ v2 vmax(v2 a, v2 b){ return __builtin_elementwise_max(a, b); }
static __device__ __forceinline__ v2 vabs(v2 a){ return __builtin_elementwise_abs(a); }
static __device__ __forceinline__ v2 vcps(v2 a, v2 b){ return __builtin_elementwise_copysign(a, b); }

static __device__ __forceinline__ v2 rsq2(v2 x){ v2 r; r.x=__builtin_amdgcn_rsqf(x.x);  r.y=__builtin_amdgcn_rsqf(x.y);  return r; }
static __device__ __forceinline__ v2 rcp2(v2 x){ v2 r; r.x=__builtin_amdgcn_rcpf(x.x);  r.y=__builtin_amdgcn_rcpf(x.y);  return r; }
static __device__ __forceinline__ v2 sqt2(v2 x){ v2 r; r.x=__builtin_amdgcn_sqrtf(x.x); r.y=__builtin_amdgcn_sqrtf(x.y); return r; }
static __device__ __forceinline__ v2 lg22(v2 x){ v2 r; r.x=__builtin_amdgcn_logf(x.x);  r.y=__builtin_amdgcn_logf(x.y);  return r; }
static __device__ __forceinline__ v2 ex22(v2 x){ v2 r; r.x=__builtin_amdgcn_exp2f(x.x); r.y=__builtin_amdgcn_exp2f(x.y); return r; }

static __device__ __forceinline__ v2 vsel(v2i m, v2 a, v2 b){
  v2i ai = __builtin_bit_cast(v2i, a), bi = __builtin_bit_cast(v2i, b);
  return __builtin_bit_cast(v2, bi ^ ((ai ^ bi) & m));
}

// Cross-lane LDS visibility fence WITHOUT vmcnt drain (prefetch stays in
// flight). "memory" clobber stops compiler reordering; lgkmcnt(0) retires
// prior ds ops; sched_barrier pins hardware-op hoisting (guide rule #18).
static __device__ __forceinline__ void lds_fence(){
  asm volatile("s_waitcnt lgkmcnt(0)" ::: "memory");
  __builtin_amdgcn_sched_barrier(0);
}

// Exact Jacobi rotation for [[app,apq],[apq,aqq]] via half-angle form.
// 1e-30f clamp is a representable normal: degenerate case -> identity, NaN-free.
__device__ __forceinline__ void jcs2(v2 app_in, v2 aqq_in, v2 apq,
                                     v2& c, v2& s,
                                     v2& app_out, v2& aqq_out)
{
  v2 d    = (aqq_in - app_in) * 0.5f;
  v2 r2   = vmax(vfma(d, d, apq * apq), V2(1e-30f));
  v2 invh = rsq2(r2);
  v2 h    = r2 * invh;                       // sqrt(d^2 + apq^2)
  v2 sg   = vcps(V2(1.0f), d);
  v2 ch   = h + vabs(d);
  v2 sh   = apq * sg;
  v2 w    = rsq2(vfma(ch, ch, sh * sh));
  c = ch * w;
  s = sh * w;
  v2 hs = h * sg;
  v2 m  = app_in + d;
  app_out = m - hs;
  aqq_out = m + hs;
}

__device__ __forceinline__ void jrot(v2& app, v2& aqq, v2& apq,
                                     v2& apk, v2& aqk,
                                     v2& vp0, v2& vp1, v2& vp2,
                                     v2& vq0, v2& vq1, v2& vq2)
{
  v2 c, s;
  jcs2(app, aqq, apq, c, s, app, aqq);
  apq = V2(0.0f);
  v2 pk = apk, qk = aqk;
  apk = c * pk - s * qk;
  aqk = s * pk + c * qk;
  v2 v;
  v = vp0; vp0 = c*v - s*vq0; vq0 = s*v + c*vq0;
  v = vp1; vp1 = c*v - s*vq1; vq1 = s*v + c*vq1;
  v = vp2; vp2 = c*v - s*vq2; vq2 = s*v + c*vq2;
}

#define CSWAP(li, lj, a0, a1, a2, b0, b1, b2)                                   \
  do {                                                                          \
    v2i _m = (li) < (lj);                                                       \
    v2 _t;                                                                      \
    _t = vsel(_m,(lj),(li)); (lj) = vsel(_m,(li),(lj)); (li) = _t;              \
    _t = vsel(_m,(b0),(a0)); (b0) = vsel(_m,(a0),(b0)); (a0) = _t;              \
    _t = vsel(_m,(b1),(a1)); (b1) = vsel(_m,(a1),(b1)); (a1) = _t;              \
    _t = vsel(_m,(b2),(a2)); (b2) = vsel(_m,(a2),(b2)); (a2) = _t;              \
  } while (0)

__global__ __launch_bounds__(TPB) void plastic_svd_kernel(
    const float* __restrict__ F,
    const float* __restrict__ p_yml,
    const float* __restrict__ p_nu,
    const float* __restrict__ p_ys,
    float* __restrict__ out,
    int nmat)
{
  __shared__ float lds[2][CH_F];             // 2 x 4.6 KB rolling buffers
  const int tid = threadIdx.x;
  const int c0  = blockIdx.x * NCH;

  // uniform scalar parameters (once per block)
  const float mu_s = __builtin_amdgcn_exp2f(p_yml[0] * 1.44269504f) *
                     __builtin_amdgcn_rcpf(2.0f * (1.0f + p_nu[0]));
  const float qy_s = p_ys[0] * 0.5f * __builtin_amdgcn_rcpf(mu_s);
  const v2 qy = V2(qy_s);

  // issue chunk-c loads into registers (coalesced 64x16B); zeros beyond range
  auto LOADS = [&](int c, float4* r, float& tail){
    const int rem = nmat - c * CHUNK;
    const int nn  = rem >= CHUNK ? CHUNK : rem;
    const int nfl = nn * 9, nfl4 = nfl >> 2;
    const float4* g4 = (const float4*)F + (size_t)c * CH_F4;
    #pragma unroll
    for (int k = 0; k < 5; ++k) {
      int i4 = k * TPB + tid;
      r[k] = make_float4(0.f, 0.f, 0.f, 0.f);
      if (i4 < nfl4) r[k] = g4[i4];
    }
    tail = 0.f;
    int e = (nfl & ~3) + tid;
    if (e < nfl) tail = F[(size_t)c * CH_F + e];
  };

  // write staged registers into LDS buffer b (carries the compiler-inserted
  // counted vmcnt wait on exactly these registers -- nothing else drains)
  auto STAGEW = [&](int c, int b, const float4* r, float tail){
    const int rem = nmat - c * CHUNK;
    const int nn  = rem >= CHUNK ? CHUNK : rem;
    const int nfl = nn * 9;
    float4* l4 = (float4*)lds[b];
    #pragma unroll
    for (int k = 0; k < 5; ++k) {
      int i4 = k * TPB + tid;
      if (i4 < CH_F4) l4[i4] = r[k];         // zeros auto-fill partial chunks
    }
    int e = (nfl & ~3) + tid;
    if (e < nfl) lds[b][e] = tail;
  };

  float4 A[5]; float tA;
  LOADS(c0, A, tA);
  STAGEW(c0, 0, A, tA);
  lds_fence();

  for (int j = 0; j < NCH; ++j) {
    const int c = c0 + j;
    const int blockBase = c * CHUNK;
    if (blockBase >= nmat) break;
    const int b = j & 1;
    const bool more = (j + 1 < NCH) && ((c + 1) * CHUNK < nmat);
    if (more) LOADS(c + 1, A, tA);           // in flight under the compute

    const int gbase = blockBase * 9;
    const int rem = nmat - blockBase;
    const int nfl = (rem >= CHUNK ? CHUNK : rem) * 9;
    const int nfl4 = nfl >> 2;
    const int mi0 = blockBase + tid;         // lane .x matrix
    const int mi1 = blockBase + TPB + tid;   // lane .y matrix
    float* bufc = lds[b];
    const float* mA = &bufc[tid * 9];        // stride-9: 2 lanes/bank, free
    const float* mB = &bufc[(TPB + tid) * 9];

    // ---- S = F^T F from LDS; F regs die after (VGPR relief in Jacobi) ----
    v2 s00, s11, s22, s01, s02, s12;
    {
      v2 f00,f01,f02,f10,f11,f12,f20,f21,f22;
      f00.x=mA[0]; f01.x=mA[1]; f02.x=mA[2];
      f10.x=mA[3]; f11.x=mA[4]; f12.x=mA[5];
      f20.x=mA[6]; f21.x=mA[7]; f22.x=mA[8];
      f00.y=mB[0]; f01.y=mB[1]; f02.y=mB[2];
      f10.y=mB[3]; f11.y=mB[4]; f12.y=mB[5];
      f20.y=mB[6]; f21.y=mB[7]; f22.y=mB[8];
      s00 = f00*f00 + f10*f10 + f20*f20;
      s11 = f01*f01 + f11*f11 + f21*f21;
      s22 = f02*f02 + f12*f12 + f22*f22;
      s01 = f00*f01 + f10*f11 + f20*f21;
      s02 = f00*f02 + f10*f12 + f20*f22;
      s12 = f01*f02 + f11*f12 + f21*f22;
    }

    v2 v00,v01,v02,v10,v11,v12,v20,v21,v22;
    v2 c_, s_;

    // ---- sweep 1, rot (0,1): V = I specialization ----
    jcs2(s00, s11, s01, c_, s_, s00, s11);
    { v2 pk = s02, qk = s12; s02 = c_*pk - s_*qk; s12 = s_*pk + c_*qk; }
    v00 = c_;  v01 = s_;
    v10 = -s_; v11 = c_;
    s01 = V2(0.0f);
    // ---- sweep 1, rot (0,2): col2 still e3, col0 = (v00,v10,0) ----
    jcs2(s00, s22, s02, c_, s_, s00, s22);
    { v2 pk = s01, qk = s12; s01 = c_*pk - s_*qk; s12 = s_*pk + c_*qk; }
    v02 = s_ * v00; v12 = s_ * v10; v22 = c_;
    v00 = c_ * v00; v10 = c_ * v10; v20 = -s_;
    v21 = V2(0.0f);
    s02 = V2(0.0f);
    // ---- sweep 1, rot (1,2) ----
    jrot(s11, s22, s12, s01, s02, v01, v11, v21, v02, v12, v22);
    // ---- sweep 2 ----
    jrot(s00, s11, s01, s02, s12, v00, v10, v20, v01, v11, v21);
    jrot(s00, s22, s02, s01, s12, v00, v10, v20, v02, v12, v22);
    jrot(s11, s22, s12, s01, s02, v01, v11, v21, v02, v12, v22);
    // ---- sweep 3 ----
    jrot(s00, s11, s01, s02, s12, v00, v10, v20, v01, v11, v21);
    jrot(s00, s22, s02, s01, s12, v00, v10, v20, v02, v12, v22);
    // final rot (1,2): couplings dead; diag still updated (closed form).
    jcs2(s11, s22, s12, c_, s_, s11, s22);
    { v2 v;
      v = v01; v01 = c_*v - s_*v02; v02 = s_*v + c_*v02;
      v = v11; v11 = c_*v - s_*v12; v12 = s_*v + c_*v12;
      v = v21; v21 = c_*v - s_*v22; v22 = s_*v + c_*v22; }

    // ---- sort eigenvalues descending (GS conditioning: R2 lesson) ----
    v2 l0 = s00, l1 = s11, l2 = s22;
    CSWAP(l0, l1, v00, v10, v20, v01, v11, v21);
    CSWAP(l1, l2, v01, v11, v21, v02, v12, v22);
    CSWAP(l0, l1, v00, v10, v20, v01, v11, v21);

    // ---- re-read F from LDS (own slots, still intact; keeps VGPR low) ----
    v2 f00,f01,f02,f10,f11,f12,f20,f21,f22;
    f00.x=mA[0]; f01.x=mA[1]; f02.x=mA[2];
    f10.x=mA[3]; f11.x=mA[4]; f12.x=mA[5];
    f20.x=mA[6]; f21.x=mA[7]; f22.x=mA[8];
    f00.y=mB[0]; f01.y=mB[1]; f02.y=mB[2];
    f10.y=mB[3]; f11.y=mB[4]; f12.y=mB[5];
    f20.y=mB[6]; f21.y=mB[7]; f22.y=mB[8];

    // ---- U: u0 = Fv0/|Fv0|; u1 = GS; u2 = u0 x u1 (sign-fixed) ----
    v2 w0x = f00*v00 + f01*v10 + f02*v20;
    v2 w0y = f10*v00 + f11*v10 + f12*v20;
    v2 w0z = f20*v00 + f21*v10 + f22*v20;
    v2 n0sq = w0x*w0x + w0y*w0y + w0z*w0z;
    v2 inv0 = rsq2(vmax(n0sq, V2(1e-30f)));
    v2 u0x = w0x*inv0, u0y = w0y*inv0, u0z = w0z*inv0;

    v2 w1x = f00*v01 + f01*v11 + f02*v21;
    v2 w1y = f10*v01 + f11*v11 + f12*v21;
    v2 w1z = f20*v01 + f21*v11 + f22*v21;
    v2 n1sq_pre = w1x*w1x + w1y*w1y + w1z*w1z;  // = sigma1^2 (pre-GS)
    v2 d01 = w1x*u0x + w1y*u0y + w1z*u0z;
    w1x = w1x - d01*u0x; w1y = w1y - d01*u0y; w1z = w1z - d01*u0z;
    v2 n1sq = w1x*w1x + w1y*w1y + w1z*w1z;
    v2 inv1 = rsq2(vmax(n1sq, V2(1e-30f)));
    v2 u1x = w1x*inv1, u1y = w1y*inv1, u1z = w1z*inv1;

    v2 u2x = u0y*u1z - u0z*u1y;
    v2 u2y = u0z*u1x - u0x*u1z;
    v2 u2z = u0x*u1y - u0y*u1x;
    v2 w2x = f00*v02 + f01*v12 + f02*v22;
    v2 w2y = f10*v02 + f11*v12 + f12*v22;
    v2 w2z = f20*v02 + f21*v12 + f22*v22;
    v2 s2d = u2x*w2x + u2y*w2y + u2z*w2z;
    v2 sg = vcps(V2(1.0f), s2d);             // sign-fix for det(U)=+1
    v2 sig2 = vabs(s2d);
    u2x = u2x * sg; u2y = u2y * sg; u2z = u2z * sg;

    // ---- von-Mises return mapping, base-2 internally ----
    v2 e0 = lg22(vmax(n0sq,     V2(1e-4f))) * 0.5f;
    v2 e1 = lg22(vmax(n1sq_pre, V2(1e-4f))) * 0.5f;
    v2 e2 = lg22(vmax(sig2,     V2(0.01f)));
    v2 m3 = (e0 + e1 + e2) * (1.0f / 3.0f);
    v2 b0 = e0 - m3, b1 = e1 - m3, b2 = e2 - m3;
    v2 bn = sqt2(b0*b0 + b1*b1 + b2*b2) * 0.69314718f + V2(1e-5f);
    v2 r = vmax(bn - qy, V2(0.0f)) * rcp2(bn);   // 0 if elastic
    v2 c0v = ex22(e0 - r * b0);
    v2 c1v = ex22(e1 - r * b1);
    v2 c2v = ex22(e2 - r * b2);

    // ---- out = sum_i c_i u_i v_i^T ----
    v2 a0x = c0v*u0x, a0y = c0v*u0y, a0z = c0v*u0z;
    v2 a1x = c1v*u1x, a1y = c1v*u1y, a1z = c1v*u1z;
    v2 a2x = c2v*u2x, a2y = c2v*u2y, a2z = c2v*u2z;

    v2 o00 = a0x*v00 + a1x*v01 + a2x*v02;
    v2 o01 = a0x*v10 + a1x*v11 + a2x*v12;
    v2 o02 = a0x*v20 + a1x*v21 + a2x*v22;
    v2 o10 = a0y*v00 + a1y*v01 + a2y*v02;
    v2 o11 = a0y*v10 + a1y*v11 + a2y*v12;
    v2 o12 = a0y*v20 + a1y*v21 + a2y*v22;
    v2 o20 = a0z*v00 + a1z*v01 + a2z*v02;
    v2 o21 = a0z*v10 + a1z*v01*0.0f + a1z*v11 + a2z*v12 - a1z*v01*0.0f;  // (expanded below)
    v2 o22 = a0z*v20 + a1z*v21 + a2z*v22;
    o21 = a0z*v10 + a1z*v11 + a2z*v12;       // keep exact R6 arithmetic

    // ---- stage outputs into bufc (F consumed; own slots only) ----
    if (mi0 < nmat) {
      float* m = &bufc[tid * 9];
      m[0]=o00.x; m[1]=o01.x; m[2]=o02.x;
      m[3]=o10.x; m[4]=o11.x; m[5]=o12.x;
      m[6]=o20.x; m[7]=o21.x; m[8]=o22.x;
    }
    if (mi1 < nmat) {
      float* m = &bufc[(TPB + tid) * 9];
      m[0]=o00.y; m[1]=o01.y; m[2]=o02.y;
      m[3]=o10.y; m[4]=o11.y; m[5]=o12.y;
      m[6]=o20.y; m[7]=o21.y; m[8]=o22.y;
    }
    lds_fence();                             // cross-lane visibility, no vmcnt

    // ---- coalesced LDS -> global store, float4-wide (fire-and-forget) ----
    {
      float4* g4 = (float4*)(out + gbase);
      const float4* l4 = (const float4*)bufc;
      #pragma unroll
      for (int k = 0; k < 5; ++k) {
        int i4 = k * TPB + tid;
        if (i4 < nfl4) g4[i4] = l4[i4];
      }
      int e = (nfl & ~3) + tid;
      if (e < nfl) out[gbase + e] = bufc[e];
    }

    if (more) {
      STAGEW(c + 1, b ^ 1, A, tA);           // vmcnt wait lands HERE (hidden)
      lds_fence();
    }
  }
}

extern "C" void kernel_launch(void* const* d_in, const int* in_sizes, int n_in,
                              void* d_out, int out_size, void* d_ws, size_t ws_size,
                              hipStream_t stream) {
  const float* F     = (const float*)d_in[0];
  const float* p_yml = (const float*)d_in[1];
  const float* p_nu  = (const float*)d_in[2];
  const float* p_ys  = (const float*)d_in[3];
  float* out = (float*)d_out;

  const int nmat = in_sizes[0] / 9;
  const int nblocks = (nmat + CHUNK * NCH - 1) / (CHUNK * NCH);
  hipLaunchKernelGGL(plastic_svd_kernel, dim3(nblocks), dim3(TPB), 0, stream,
                     F, p_yml, p_nu, p_ys, out, nmat);
}